// Round 3
// baseline (407.159 us; speedup 1.0000x reference)
//
#include <hip/hip_runtime.h>

typedef _Float16 f16;
typedef __attribute__((__ext_vector_type__(4))) _Float16 f16x4;
typedef __attribute__((__ext_vector_type__(8))) _Float16 f16x8;
typedef __attribute__((__ext_vector_type__(4))) float f32x4;

#define GLDS16(g, l) __builtin_amdgcn_global_load_lds( \
    (const __attribute__((address_space(1))) void*)(g), \
    (__attribute__((address_space(3))) void*)(l), 16, 0, 0)

// ---------------- constants ----------------
// x: (16,256,56,56)  w1: (128,256,7,7) dil=2 pad=6 -> k:(16,128,56,56)
// w2: (49,128) -> attn (16,49,56,56); out = sum_ij tap(x) * attn
// P_TOT = 16*56*56 = 50176 positions, padded spatial 68x68.

__global__ void zero_fill(uint4* __restrict__ p, int n) {
  for (int i = blockIdx.x * blockDim.x + threadIdx.x; i < n;
       i += gridDim.x * blockDim.x)
    p[i] = make_uint4(0u, 0u, 0u, 0u);
}

// x NCHW fp32 -> xpad NHWC fp16, padded 6 on each spatial side (68x68)
__global__ __launch_bounds__(256) void transpose_cast(
    const float* __restrict__ x, f16* __restrict__ xpad) {
  __shared__ float t[256][57];
  const int bh = blockIdx.x;           // b*56 + h
  const int h = bh % 56, b = bh / 56;
  const float* xp = x + (size_t)b * 256 * 3136 + h * 56;
  for (int f = threadIdx.x; f < 256 * 56; f += 256) {
    int c = f / 56, w = f % 56;
    t[c][w] = xp[(size_t)c * 3136 + w];
  }
  __syncthreads();
  f16* op = xpad + (((size_t)(b * 68) + h + 6) * 68 + 6) * 256;
  for (int g = threadIdx.x; g < 56 * 256; g += 256) {
    int w = g / 256, c = g % 256;
    op[(size_t)w * 256 + c] = (f16)t[c][w];
  }
}

// w1 (co,c,i,j) fp32 -> w1h[ij][co][c] fp16
__global__ void w1_transform(const float* __restrict__ w1, f16* __restrict__ w1h) {
  int idx = blockIdx.x * 256 + threadIdx.x;
  if (idx >= 49 * 128 * 256) return;
  int c = idx & 255;
  int rest = idx >> 8;
  int co = rest & 127;
  int ij = rest >> 7;
  w1h[idx] = (f16)w1[((size_t)co * 256 + c) * 49 + ij];
}

// ---------------- conv1 as implicit GEMM (MFMA fp16), K-split 2 ----------
// M=50176, N=128, K = 49 taps x 256 ch. Each block does one 128x128 tile
// over HALF the channels (0-127 or 128-255): 49 taps x 4 cc-steps = 196
// K-steps of 32. Grid 784 = ~3 blocks/CU (m97 operating point).
// Partials stored fp16; conv2 sums halves + bias + relu.
__global__ __launch_bounds__(256, 3) void conv1_gemm(
    const f16* __restrict__ xpad, const f16* __restrict__ w1h,
    f16* __restrict__ kbuf) {
  __shared__ f16 Asm[128 * 32];
  __shared__ f16 Bsm[128 * 32];

  const int tid = threadIdx.x;
  const int wid = tid >> 6;
  const int lane = tid & 63;
  const int bid = blockIdx.x;
  const int tile = bid >> 1;
  const int half = bid & 1;
  const int m0 = tile * 128;
  const int chbase = half * 256;  // byte offset of channel-half in 512B row

  // staging: each wave stages rows [wid*32, wid*32+32) in 2 issues of 16 rows
  const int rq0 = wid * 32 + (lane >> 2);
  const int rq1 = rq0 + 16;
  const int sub = (lane & 3) * 16;  // byte offset within 64B (32ch) row slice

  auto pos_byte = [&](int r) -> int {
    int P = m0 + r;
    int bb = P / 3136;
    int rem = P - bb * 3136;
    int hh = rem / 56;
    int ww = rem - hh * 56;
    return ((bb * 68 + hh) * 68 + ww) * 512;
  };
  const int pA0 = pos_byte(rq0) + chbase + sub;
  const int pA1 = pos_byte(rq1) + chbase + sub;
  const int pB0 = rq0 * 512 + chbase + sub;
  const int pB1 = rq1 * 512 + chbase + sub;

  const char* xb = (const char*)xpad;
  const char* wb = (const char*)w1h;
  char* As = (char*)Asm;
  char* Bs = (char*)Bsm;
  const int ldsq = wid * 2048;

  const int wr = wid >> 1, wc = wid & 1;
  const int fo = (lane & 15) * 64 + (lane >> 4) * 16;
  const int aoff = wr * 4096 + fo;
  const int boff = wc * 4096 + fo;

  f32x4 acc[4][4] = {};

  for (int ij = 0; ij < 49; ++ij) {
    const int tap = ((ij / 7) * 136 + (ij % 7) * 2) * 512;  // (2i*68+2j)*512B
    const char* ga0 = xb + pA0 + tap;
    const char* ga1 = xb + pA1 + tap;
    const char* gb0 = wb + ij * 65536 + pB0;
    const char* gb1 = wb + ij * 65536 + pB1;
    for (int cc = 0; cc < 4; ++cc) {
      const int cb = cc * 64;  // 32 channels * 2B
      __syncthreads();
      GLDS16(ga0 + cb, As + ldsq);
      GLDS16(ga1 + cb, As + ldsq + 1024);
      GLDS16(gb0 + cb, Bs + ldsq);
      GLDS16(gb1 + cb, Bs + ldsq + 1024);
      __syncthreads();
      f16x8 af[4], bf[4];
#pragma unroll
      for (int m = 0; m < 4; ++m)
        af[m] = *(const f16x8*)(As + aoff + m * 1024);
#pragma unroll
      for (int n = 0; n < 4; ++n)
        bf[n] = *(const f16x8*)(Bs + boff + n * 1024);
#pragma unroll
      for (int m = 0; m < 4; ++m)
#pragma unroll
        for (int n = 0; n < 4; ++n)
          acc[m][n] = __builtin_amdgcn_mfma_f32_16x16x32_f16(
              af[m], bf[n], acc[m][n], 0, 0, 0);
    }
  }

  f16* kh = kbuf + (size_t)half * (50176 * 128);
#pragma unroll
  for (int m = 0; m < 4; ++m) {
    const int row0 = m0 + wr * 64 + m * 16 + (lane >> 4) * 4;
#pragma unroll
    for (int n = 0; n < 4; ++n) {
      const int co = wc * 64 + n * 16 + (lane & 15);
#pragma unroll
      for (int r = 0; r < 4; ++r)
        kh[(size_t)(row0 + r) * 128 + co] = (f16)acc[m][n][r];
    }
  }
}

// ---------------- sum halves + bias + relu + 1x1 + BN + softmax ---------
__global__ __launch_bounds__(64, 4) void conv2_bn_softmax(
    const f16* __restrict__ kbuf, const float* __restrict__ b1,
    const float* __restrict__ w2, const float* __restrict__ b2,
    const float* __restrict__ gamma, const float* __restrict__ beta,
    const float* __restrict__ rmean, const float* __restrict__ rvar,
    float* __restrict__ attn) {
  __shared__ float w2s[49 * 128];
  __shared__ float b1s[128];
  __shared__ float outs[64 * 49];
  for (int i = threadIdx.x; i < 49 * 128; i += 64) w2s[i] = w2[i];
  for (int i = threadIdx.x; i < 128; i += 64) b1s[i] = b1[i];
  __syncthreads();
  const int p = blockIdx.x * 64 + threadIdx.x;
  float acc[49];
#pragma unroll
  for (int o = 0; o < 49; ++o) acc[o] = 0.f;
  const f16x8* ka = (const f16x8*)(kbuf + (size_t)p * 128);
  const f16x8* kb = (const f16x8*)(kbuf + (size_t)50176 * 128 + (size_t)p * 128);
  for (int u = 0; u < 16; ++u) {
    f16x8 va = ka[u], vb = kb[u];
    float kv[8];
#pragma unroll
    for (int j = 0; j < 8; ++j) {
      float s = (float)va[j] + (float)vb[j] + b1s[u * 8 + j];
      kv[j] = s > 0.f ? s : 0.f;
    }
#pragma unroll
    for (int o = 0; o < 49; ++o) {
      const float* wrow = w2s + o * 128 + u * 8;
#pragma unroll
      for (int j = 0; j < 8; ++j) acc[o] = fmaf(kv[j], wrow[j], acc[o]);
    }
  }
  float mx = -1e30f;
#pragma unroll
  for (int o = 0; o < 49; ++o) {
    float s = acc[o] + b2[o];
    float inv = gamma[o] * rsqrtf(rvar[o] + 1e-5f);
    s = (s - rmean[o]) * inv + beta[o];
    s = s > 0.f ? s : 0.f;
    acc[o] = s;
    mx = fmaxf(mx, s);
  }
  float sum = 0.f;
#pragma unroll
  for (int o = 0; o < 49; ++o) {
    float e = __expf(acc[o] - mx);
    acc[o] = e;
    sum += e;
  }
  const float rinv = 1.f / sum;
  float* orow = outs + threadIdx.x * 49;
#pragma unroll
  for (int o = 0; o < 49; ++o) orow[o] = acc[o] * rinv;
  __syncthreads();
  float* ab = attn + (size_t)blockIdx.x * (64 * 49);
  for (int i = threadIdx.x; i < 64 * 49; i += 64) ab[i] = outs[i];
}

// ---------------- attention-weighted aggregation (v2) ----------------
__global__ __launch_bounds__(896, 1) void aggregate2(
    const f16* __restrict__ xpad, const float* __restrict__ attn,
    float* __restrict__ out) {
  __shared__ float t[256][57];  // 58368 B
  const int bh = blockIdx.x;
  const int h = bh % 56, b = bh / 56;
  const int tid = threadIdx.x;
  const int wid = tid >> 6, lane = tid & 63;
  const int q = (wid < 7) ? wid * 8 : (wid - 7) * 8 + 1;

  int ap[4];
#pragma unroll
  for (int p = 0; p < 4; ++p) ap[p] = ((b * 56 + h) * 56 + q + 2 * p) * 49;

  float acc[4][4] = {};
  const f16* rowb = xpad + ((size_t)(b * 68 + h) * 68 + q) * 256 + 4 * lane;

  for (int i = 0; i < 7; ++i) {
    const f16* rb = rowb + (size_t)(2 * i * 68) * 256;
#pragma unroll
    for (int tt = 0; tt < 10; ++tt) {
      f16x4 xv = *(const f16x4*)(rb + tt * 512);  // 2 cols per tt step
      float xf[4];
#pragma unroll
      for (int k = 0; k < 4; ++k) xf[k] = (float)xv[k];
#pragma unroll
      for (int p = 0; p < 4; ++p) {
        const int j = tt - p;
        if (j >= 0 && j < 7) {
          const float a = attn[ap[p] + i * 7 + j];
#pragma unroll
          for (int k = 0; k < 4; ++k) acc[p][k] = fmaf(a, xf[k], acc[p][k]);
        }
      }
    }
  }

#pragma unroll
  for (int p = 0; p < 4; ++p)
#pragma unroll
    for (int k = 0; k < 4; ++k) t[4 * lane + k][q + 2 * p] = acc[p][k];
  __syncthreads();
  float* ob = out + ((size_t)b * 256 * 56 + h) * 56;
  for (int f = tid; f < 256 * 56; f += 896) {
    int c = f / 56, w = f % 56;
    ob[(size_t)c * 3136 + w] = t[c][w];
  }
}

// ---------------- launch ----------------
extern "C" void kernel_launch(void* const* d_in, const int* in_sizes, int n_in,
                              void* d_out, int out_size, void* d_ws,
                              size_t ws_size, hipStream_t stream) {
  const float* x = (const float*)d_in[0];
  const float* w1 = (const float*)d_in[1];
  const float* b1 = (const float*)d_in[2];
  const float* w2 = (const float*)d_in[3];
  const float* b2 = (const float*)d_in[4];
  const float* gamma = (const float*)d_in[5];
  const float* beta = (const float*)d_in[6];
  const float* rmean = (const float*)d_in[7];
  const float* rvar = (const float*)d_in[8];
  float* out = (float*)d_out;

  char* ws = (char*)d_ws;
  f16* xpad = (f16*)ws;                     // 16*68*68*256*2 = 37,879,808 B
  f16* w1h = (f16*)(ws + 37879808);         // 49*128*256*2  =  3,211,264 B
  f16* kbuf = (f16*)(ws + 41091072);        // 2*50176*128*2 = 25,690,112 B
  float* attn = (float*)(ws + 66781184);    // 50176*49*4    =  9,834,496 B

  hipLaunchKernelGGL(zero_fill, dim3(2048), dim3(256), 0, stream, (uint4*)xpad,
                     2367488);
  hipLaunchKernelGGL(transpose_cast, dim3(896), dim3(256), 0, stream, x, xpad);
  hipLaunchKernelGGL(w1_transform, dim3(6272), dim3(256), 0, stream, w1, w1h);
  hipLaunchKernelGGL(conv1_gemm, dim3(784), dim3(256), 0, stream, xpad, w1h,
                     kbuf);
  hipLaunchKernelGGL(conv2_bn_softmax, dim3(784), dim3(64), 0, stream, kbuf,
                     b1, w2, b2, gamma, beta, rmean, rvar, attn);
  hipLaunchKernelGGL(aggregate2, dim3(896), dim3(896), 0, stream, xpad, attn,
                     out);
}

// Round 4
// 369.985 us; speedup vs baseline: 1.1005x; 1.1005x over previous
//
#include <hip/hip_runtime.h>

typedef _Float16 f16;
typedef __attribute__((__ext_vector_type__(4))) _Float16 f16x4;
typedef __attribute__((__ext_vector_type__(8))) _Float16 f16x8;
typedef __attribute__((__ext_vector_type__(4))) float f32x4;

#define GLDS16(g, l) __builtin_amdgcn_global_load_lds( \
    (const __attribute__((address_space(1))) void*)(g), \
    (__attribute__((address_space(3))) void*)(l), 16, 0, 0)

// ---------------- constants ----------------
// x: (16,256,56,56)  w1: (128,256,7,7) dil=2 pad=6 -> k:(16,128,56,56)
// w2: (49,128) -> attn (16,49,56,56); out = sum_ij tap(x) * attn
// padded spatial 68x68 (orig (h,w) at padded (h+6,w+6); tap (i,j) of output
// (h,w) reads padded array index (h+2i, w+2j)).

__global__ void zero_fill(uint4* __restrict__ p, int n) {
  for (int i = blockIdx.x * blockDim.x + threadIdx.x; i < n;
       i += gridDim.x * blockDim.x)
    p[i] = make_uint4(0u, 0u, 0u, 0u);
}

// x NCHW fp32 -> xpad NHWC fp16, padded 6 each side (68x68)
__global__ __launch_bounds__(256) void transpose_cast(
    const float* __restrict__ x, f16* __restrict__ xpad) {
  __shared__ float t[256][57];
  const int bh = blockIdx.x;           // b*56 + h
  const int h = bh % 56, b = bh / 56;
  const float* xp = x + (size_t)b * 256 * 3136 + h * 56;
  for (int f = threadIdx.x; f < 256 * 56; f += 256) {
    int c = f / 56, w = f % 56;
    t[c][w] = xp[(size_t)c * 3136 + w];
  }
  __syncthreads();
  f16* op = xpad + (((size_t)(b * 68) + h + 6) * 68 + 6) * 256;
  for (int g = threadIdx.x; g < 56 * 256; g += 256) {
    int w = g / 256, c = g % 256;
    op[(size_t)w * 256 + c] = (f16)t[c][w];
  }
}

// w1 (co,c,i,j) fp32 -> w1h[ij][co][c] fp16
__global__ void w1_transform(const float* __restrict__ w1, f16* __restrict__ w1h) {
  int idx = blockIdx.x * 256 + threadIdx.x;
  if (idx >= 49 * 128 * 256) return;
  int c = idx & 255;
  int rest = idx >> 8;
  int co = rest & 127;
  int ij = rest >> 7;
  w1h[idx] = (f16)w1[((size_t)co * 256 + c) * 49 + ij];
}

// ---------------- conv1: row-strip implicit GEMM (MFMA fp16) -------------
// Block = (b, hpair, channel-half). M-tile = 112 positions (2 image rows,
// exactly 7 m-frags). A: 14x68 padded-row strip x 32ch staged ONCE per
// cc-slice (61KB LDS) and reused by all 49 taps. B staged per tap-PAIR
// (16KB) -> 28 MFMA/wave per stage step. K-half split keeps 896 blocks.
__global__ __launch_bounds__(256, 2) void conv1_gemm(
    const f16* __restrict__ xpad, const f16* __restrict__ w1h,
    f16* __restrict__ kbuf) {
  __shared__ f16 strip[14 * 68 * 32];  // 60928 B  [r][col][ch32]
  __shared__ f16 Bsm[2 * 128 * 32];    // 16384 B  [tap][co][ch32]

  const int tid = threadIdx.x;
  const int wid = tid >> 6, lane = tid & 63;
  // XCD-chunked bijective swizzle (896 % 8 == 0): halves of one strip and
  // neighboring strips land on the same XCD's L2.
  const int pphys = blockIdx.x;
  const int bid = (pphys & 7) * 112 + (pphys >> 3);
  const int half = bid & 1;
  const int bhp = bid >> 1;            // 0..447
  const int hp = bhp % 28, b = bhp / 28;
  const int h0 = hp * 2;

  // per-lane M-row precompute for the 7 m-frags (position p = m*16+(lane&15))
  int arow_off[7];
#pragma unroll
  for (int m = 0; m < 7; ++m) {
    int p = m * 16 + (lane & 15);
    int rw = (p >= 56) ? 1 : 0;
    int w = p - 56 * rw;
    arow_off[m] = (rw * 68 + w) * 64 + (lane >> 4) * 16;
  }
  const int boff0 = (wid * 32 + (lane & 15)) * 64 + (lane >> 4) * 16;

  const char* xg = (const char*)xpad +
                   ((size_t)(b * 68 + h0)) * (68 * 512) + half * 256;
  const char* wg = (const char*)w1h + half * 256;
  char* Ss = (char*)strip;
  char* Bs = (char*)Bsm;

  f32x4 acc[7][2] = {};

  for (int cc = 0; cc < 4; ++cc) {
    const int chb = cc * 64;  // byte offset of 32-ch slice within the half
    // ---- stage strip: 3808 16B slots, 15 rounds ----
    __syncthreads();
#pragma unroll
    for (int rr = 0; rr < 15; ++rr) {
      int s = rr * 256 + tid;
      if (s < 3808) {
        int r = (int)((unsigned)s / 272u);
        int rem = s - r * 272;
        int col = rem >> 2, q = rem & 3;
        GLDS16(xg + (size_t)r * (68 * 512) + col * 512 + chb + q * 16,
               Ss + (rr * 256 + wid * 64) * 16);
      }
    }
    __syncthreads();

    // ---- tap loop: 24 pairs + 1 single ----
    for (int pt = 0; pt < 25; ++pt) {
      const int ij0 = pt * 2;
      const bool full = (pt < 24);
      __syncthreads();  // prior consumers done with Bsm
      // stage B: tap ij0 (512 slots) + optionally ij0+1
#pragma unroll
      for (int rr = 0; rr < 2; ++rr) {
        int s = rr * 256 + tid;
        int co = s >> 2, q = s & 3;
        GLDS16(wg + (size_t)ij0 * 65536 + co * 512 + chb + q * 16,
               Bs + (rr * 256 + wid * 64) * 16);
      }
      if (full) {
#pragma unroll
        for (int rr = 2; rr < 4; ++rr) {
          int s = rr * 256 + tid;          // 512..1023
          int rem = s & 511;
          int co = rem >> 2, q = rem & 3;
          GLDS16(wg + (size_t)(ij0 + 1) * 65536 + co * 512 + chb + q * 16,
                 Bs + (rr * 256 + wid * 64) * 16);
        }
      }
      __syncthreads();  // drain (compiler emits vmcnt(0) before barrier)

      // compute
      auto do_tap = [&](int t) {
        const int ij = ij0 + t;
        const int i = (int)((unsigned)ij / 7u);
        const int j = ij - 7 * i;
        const int tof = i * 8704 + j * 128;  // (2i*68 + 2j)*64 bytes
        f16x8 bf0 = *(const f16x8*)(Bs + t * 8192 + boff0);
        f16x8 bf1 = *(const f16x8*)(Bs + t * 8192 + boff0 + 1024);
#pragma unroll
        for (int m = 0; m < 7; ++m) {
          f16x8 a = *(const f16x8*)(Ss + arow_off[m] + tof);
          acc[m][0] = __builtin_amdgcn_mfma_f32_16x16x32_f16(a, bf0,
                                                             acc[m][0], 0, 0, 0);
          acc[m][1] = __builtin_amdgcn_mfma_f32_16x16x32_f16(a, bf1,
                                                             acc[m][1], 0, 0, 0);
        }
      };
      do_tap(0);
      if (full) do_tap(1);
    }
  }

  // write fp16 partials: kh[p][co], p = (b*56 + h0 + rw)*56 + w
  f16* kh = kbuf + (size_t)half * (50176 * 128);
  const int pbase = (b * 56 + h0) * 56;
#pragma unroll
  for (int m = 0; m < 7; ++m) {
#pragma unroll
    for (int n = 0; n < 2; ++n) {
      const int co = wid * 32 + n * 16 + (lane & 15);
#pragma unroll
      for (int r = 0; r < 4; ++r) {
        int p = m * 16 + (lane >> 4) * 4 + r;
        int rw = (p >= 56) ? 1 : 0;
        int w = p - 56 * rw;
        kh[(size_t)(pbase + rw * 56 + w) * 128 + co] = (f16)acc[m][n][r];
      }
    }
  }
}

// ---------------- sum halves + bias + relu + 1x1 + BN + softmax ---------
// 128 threads, 392 blocks; LDS ~50KB -> 3 blocks/CU.
__global__ __launch_bounds__(128) void conv2_bn_softmax(
    const f16* __restrict__ kbuf, const float* __restrict__ b1,
    const float* __restrict__ w2, const float* __restrict__ b2,
    const float* __restrict__ gamma, const float* __restrict__ beta,
    const float* __restrict__ rmean, const float* __restrict__ rvar,
    float* __restrict__ attn) {
  __shared__ float w2s[49 * 128];
  __shared__ float b1s[128];
  __shared__ float outs[128 * 49];
  for (int i = threadIdx.x; i < 49 * 128; i += 128) w2s[i] = w2[i];
  if (threadIdx.x < 128) b1s[threadIdx.x] = b1[threadIdx.x];
  __syncthreads();
  const int p = blockIdx.x * 128 + threadIdx.x;
  float acc[49];
#pragma unroll
  for (int o = 0; o < 49; ++o) acc[o] = 0.f;
  const f16x8* ka = (const f16x8*)(kbuf + (size_t)p * 128);
  const f16x8* kb = (const f16x8*)(kbuf + (size_t)50176 * 128 + (size_t)p * 128);
  for (int u = 0; u < 16; ++u) {
    f16x8 va = ka[u], vb = kb[u];
    float kv[8];
#pragma unroll
    for (int j = 0; j < 8; ++j) {
      float s = (float)va[j] + (float)vb[j] + b1s[u * 8 + j];
      kv[j] = s > 0.f ? s : 0.f;
    }
#pragma unroll
    for (int o = 0; o < 49; ++o) {
      const float* wrow = w2s + o * 128 + u * 8;
#pragma unroll
      for (int j = 0; j < 8; ++j) acc[o] = fmaf(kv[j], wrow[j], acc[o]);
    }
  }
  float mx = -1e30f;
#pragma unroll
  for (int o = 0; o < 49; ++o) {
    float s = acc[o] + b2[o];
    float inv = gamma[o] * rsqrtf(rvar[o] + 1e-5f);
    s = (s - rmean[o]) * inv + beta[o];
    s = s > 0.f ? s : 0.f;
    acc[o] = s;
    mx = fmaxf(mx, s);
  }
  float sum = 0.f;
#pragma unroll
  for (int o = 0; o < 49; ++o) {
    float e = __expf(acc[o] - mx);
    acc[o] = e;
    sum += e;
  }
  const float rinv = 1.f / sum;
  float* orow = outs + threadIdx.x * 49;
#pragma unroll
  for (int o = 0; o < 49; ++o) orow[o] = acc[o] * rinv;
  __syncthreads();
  float* ab = attn + (size_t)blockIdx.x * (128 * 49);
  for (int i = threadIdx.x; i < 128 * 49; i += 128) ab[i] = outs[i];
}

// ---------------- attention-weighted aggregation ----------------
__global__ __launch_bounds__(896, 1) void aggregate2(
    const f16* __restrict__ xpad, const float* __restrict__ attn,
    float* __restrict__ out) {
  __shared__ float t[256][57];  // 58368 B
  const int bh = blockIdx.x;
  const int h = bh % 56, b = bh / 56;
  const int tid = threadIdx.x;
  const int wid = tid >> 6, lane = tid & 63;
  const int q = (wid < 7) ? wid * 8 : (wid - 7) * 8 + 1;

  int ap[4];
#pragma unroll
  for (int p = 0; p < 4; ++p) ap[p] = ((b * 56 + h) * 56 + q + 2 * p) * 49;

  float acc[4][4] = {};
  const f16* rowb = xpad + ((size_t)(b * 68 + h) * 68 + q) * 256 + 4 * lane;

  for (int i = 0; i < 7; ++i) {
    const f16* rb = rowb + (size_t)(2 * i * 68) * 256;
#pragma unroll
    for (int tt = 0; tt < 10; ++tt) {
      f16x4 xv = *(const f16x4*)(rb + tt * 512);  // 2 cols per tt step
      float xf[4];
#pragma unroll
      for (int k = 0; k < 4; ++k) xf[k] = (float)xv[k];
#pragma unroll
      for (int p = 0; p < 4; ++p) {
        const int j = tt - p;
        if (j >= 0 && j < 7) {
          const float a = attn[ap[p] + i * 7 + j];
#pragma unroll
          for (int k = 0; k < 4; ++k) acc[p][k] = fmaf(a, xf[k], acc[p][k]);
        }
      }
    }
  }

#pragma unroll
  for (int p = 0; p < 4; ++p)
#pragma unroll
    for (int k = 0; k < 4; ++k) t[4 * lane + k][q + 2 * p] = acc[p][k];
  __syncthreads();
  float* ob = out + ((size_t)b * 256 * 56 + h) * 56;
  for (int f = tid; f < 256 * 56; f += 896) {
    int c = f / 56, w = f % 56;
    ob[(size_t)c * 3136 + w] = t[c][w];
  }
}

// ---------------- launch ----------------
extern "C" void kernel_launch(void* const* d_in, const int* in_sizes, int n_in,
                              void* d_out, int out_size, void* d_ws,
                              size_t ws_size, hipStream_t stream) {
  const float* x = (const float*)d_in[0];
  const float* w1 = (const float*)d_in[1];
  const float* b1 = (const float*)d_in[2];
  const float* w2 = (const float*)d_in[3];
  const float* b2 = (const float*)d_in[4];
  const float* gamma = (const float*)d_in[5];
  const float* beta = (const float*)d_in[6];
  const float* rmean = (const float*)d_in[7];
  const float* rvar = (const float*)d_in[8];
  float* out = (float*)d_out;

  char* ws = (char*)d_ws;
  f16* xpad = (f16*)ws;                     // 16*68*68*256*2 = 37,879,808 B
  f16* w1h = (f16*)(ws + 37879808);         // 49*128*256*2  =  3,211,264 B
  f16* kbuf = (f16*)(ws + 41091072);        // 2*50176*128*2 = 25,690,112 B
  float* attn = (float*)(ws + 66781184);    // 50176*49*4    =  9,834,496 B

  hipLaunchKernelGGL(zero_fill, dim3(2048), dim3(256), 0, stream, (uint4*)xpad,
                     2367488);
  hipLaunchKernelGGL(transpose_cast, dim3(896), dim3(256), 0, stream, x, xpad);
  hipLaunchKernelGGL(w1_transform, dim3(6272), dim3(256), 0, stream, w1, w1h);
  hipLaunchKernelGGL(conv1_gemm, dim3(896), dim3(256), 0, stream, xpad, w1h,
                     kbuf);
  hipLaunchKernelGGL(conv2_bn_softmax, dim3(392), dim3(128), 0, stream, kbuf,
                     b1, w2, b2, gamma, beta, rmean, rvar, attn);
  hipLaunchKernelGGL(aggregate2, dim3(896), dim3(896), 0, stream, xpad, attn,
                     out);
}

// Round 5
// 332.566 us; speedup vs baseline: 1.2243x; 1.1125x over previous
//
#include <hip/hip_runtime.h>

typedef _Float16 f16;
typedef __attribute__((__ext_vector_type__(4))) _Float16 f16x4;
typedef __attribute__((__ext_vector_type__(8))) _Float16 f16x8;
typedef __attribute__((__ext_vector_type__(4))) float f32x4;

#define GLDS16(g, l) __builtin_amdgcn_global_load_lds( \
    (const __attribute__((address_space(1))) void*)(g), \
    (__attribute__((address_space(3))) void*)(l), 16, 0, 0)

// ---------------- constants ----------------
// x: (16,256,56,56)  w1: (128,256,7,7) dil=2 pad=6 -> k:(16,128,56,56)
// w2: (49,128) -> attn (16,49,56,56); out = sum_ij tap(x) * attn
// padded spatial 68x68 (orig (h,w) at padded (h+6,w+6); tap (i,j) of output
// (h,w) reads padded array index (h+2i, w+2j)).

__global__ void zero_fill(uint4* __restrict__ p, int n) {
  for (int i = blockIdx.x * blockDim.x + threadIdx.x; i < n;
       i += gridDim.x * blockDim.x)
    p[i] = make_uint4(0u, 0u, 0u, 0u);
}

// x NCHW fp32 -> xpad NHWC fp16, padded 6 each side (68x68)
__global__ __launch_bounds__(256) void transpose_cast(
    const float* __restrict__ x, f16* __restrict__ xpad) {
  __shared__ float t[256][57];
  const int bh = blockIdx.x;           // b*56 + h
  const int h = bh % 56, b = bh / 56;
  const float* xp = x + (size_t)b * 256 * 3136 + h * 56;
  for (int f = threadIdx.x; f < 256 * 56; f += 256) {
    int c = f / 56, w = f % 56;
    t[c][w] = xp[(size_t)c * 3136 + w];
  }
  __syncthreads();
  f16* op = xpad + (((size_t)(b * 68) + h + 6) * 68 + 6) * 256;
  for (int g = threadIdx.x; g < 56 * 256; g += 256) {
    int w = g / 256, c = g % 256;
    op[(size_t)w * 256 + c] = (f16)t[c][w];
  }
}

// w1 (co,c,i,j) fp32 -> per-wave-fragment lane order:
// idx = ((((ij*2+half)*4+cc)*8 + f)*64 + lane)*8 + e
//   co = (f>>1)*32 + (f&1)*16 + (lane&15)
//   c  = half*128 + cc*32 + (lane>>4)*8 + e
// so each (ij,half,cc,f) fragment is one contiguous 1KB wave-load.
__global__ void w1_transform(const float* __restrict__ w1, f16* __restrict__ w1h) {
  int idx = blockIdx.x * 256 + threadIdx.x;
  if (idx >= 49 * 128 * 256) return;
  int e = idx & 7;
  int lane = (idx >> 3) & 63;
  int f = (idx >> 9) & 7;
  int cc = (idx >> 12) & 3;
  int half = (idx >> 14) & 1;
  int ij = idx >> 15;  // 0..48
  int co = (f >> 1) * 32 + (f & 1) * 16 + (lane & 15);
  int c = half * 128 + cc * 32 + (lane >> 4) * 8 + e;
  w1h[idx] = (f16)w1[((size_t)co * 256 + c) * 49 + ij];
}

// ---------------- conv1: row-strip implicit GEMM, barrier-free taps -----
// Block = (b, hpair, channel-half). M-tile = 112 positions (2 rows, 7
// m-frags). A: 14x68x32ch strip staged once per cc slice (61KB LDS),
// reused by all 49 taps. B: straight global->register fragment loads
// (coalesced 1KB wave-loads, L2-hot), prefetched 1 tap ahead. NO per-tap
// barriers -- only 2 per strip restage (8 total).
__global__ __launch_bounds__(256, 2) void conv1_gemm(
    const f16* __restrict__ xpad, const f16* __restrict__ w1h,
    f16* __restrict__ kbuf) {
  __shared__ f16 strip[14 * 68 * 32];  // 60928 B  [r][col][ch32]

  const int tid = threadIdx.x;
  const int wid = tid >> 6, lane = tid & 63;
  // XCD-chunked bijective swizzle (896 % 8 == 0)
  const int pphys = blockIdx.x;
  const int bid = (pphys & 7) * 112 + (pphys >> 3);
  const int half = bid & 1;
  const int bhp = bid >> 1;  // 0..447
  const int hp = bhp % 28, b = bhp / 28;
  const int h0 = hp * 2;

  int arow_off[7];
#pragma unroll
  for (int m = 0; m < 7; ++m) {
    int p = m * 16 + (lane & 15);
    int rw = (p >= 56) ? 1 : 0;
    int w = p - 56 * rw;
    arow_off[m] = (rw * 68 + w) * 64 + (lane >> 4) * 16;
  }

  const char* xg = (const char*)xpad +
                   ((size_t)(b * 68 + h0)) * (68 * 512) + half * 256;
  const char* wB = (const char*)w1h;
  char* Ss = (char*)strip;

  const int half4 = half * 4;
  const int wid2 = wid * 2;
  auto loadB = [&](int cc, int ij, int n) -> f16x8 {
    int off = (((ij * 8 + half4 + cc) * 8 + wid2 + n) * 64 + lane) * 16;
    return *(const f16x8*)(wB + off);
  };

  f32x4 acc[7][2] = {};
  f16x8 pb0 = loadB(0, 0, 0), pb1 = loadB(0, 0, 1);

  for (int cc = 0; cc < 4; ++cc) {
    const int chb = cc * 64;  // byte offset of 32-ch slice within the half
    __syncthreads();          // prior cc's consumers done with strip
#pragma unroll
    for (int rr = 0; rr < 15; ++rr) {
      int s = rr * 256 + tid;
      if (s < 3808) {
        int r = (int)((unsigned)s / 272u);
        int rem = s - r * 272;
        int col = rem >> 2, q = rem & 3;
        GLDS16(xg + (size_t)r * (68 * 512) + col * 512 + chb + q * 16,
               Ss + (rr * 256 + wid * 64) * 16);
      }
    }
    __syncthreads();  // strip ready (compiler drains vmcnt before barrier)

    for (int ij = 0; ij < 49; ++ij) {
      f16x8 b0 = pb0, b1 = pb1;
      int nij = ij + 1, ncc = cc;
      if (nij == 49) { nij = 0; ++ncc; }
      if (ncc < 4) {
        pb0 = loadB(ncc, nij, 0);
        pb1 = loadB(ncc, nij, 1);
      }
      const int i = (int)((unsigned)ij / 7u);
      const int j = ij - 7 * i;
      const int tof = i * 8704 + j * 128;  // (2i*68 + 2j)*64 bytes
#pragma unroll
      for (int m = 0; m < 7; ++m) {
        f16x8 a = *(const f16x8*)(Ss + arow_off[m] + tof);
        acc[m][0] = __builtin_amdgcn_mfma_f32_16x16x32_f16(a, b0,
                                                           acc[m][0], 0, 0, 0);
        acc[m][1] = __builtin_amdgcn_mfma_f32_16x16x32_f16(a, b1,
                                                           acc[m][1], 0, 0, 0);
      }
    }
  }

  // write fp16 partials: kh[p][co], p = (b*56 + h0 + rw)*56 + w
  f16* kh = kbuf + (size_t)half * (50176 * 128);
  const int pbase = (b * 56 + h0) * 56;
#pragma unroll
  for (int m = 0; m < 7; ++m) {
#pragma unroll
    for (int n = 0; n < 2; ++n) {
      const int co = wid * 32 + n * 16 + (lane & 15);
#pragma unroll
      for (int r = 0; r < 4; ++r) {
        int p = m * 16 + (lane >> 4) * 4 + r;
        int rw = (p >= 56) ? 1 : 0;
        int w = p - 56 * rw;
        kh[(size_t)(pbase + rw * 56 + w) * 128 + co] = (f16)acc[m][n][r];
      }
    }
  }
}

// ---------------- sum halves + bias + relu + 1x1 + BN + softmax ---------
__global__ __launch_bounds__(128) void conv2_bn_softmax(
    const f16* __restrict__ kbuf, const float* __restrict__ b1,
    const float* __restrict__ w2, const float* __restrict__ b2,
    const float* __restrict__ gamma, const float* __restrict__ beta,
    const float* __restrict__ rmean, const float* __restrict__ rvar,
    float* __restrict__ attn) {
  __shared__ float w2s[49 * 128];
  __shared__ float b1s[128];
  __shared__ float outs[128 * 49];
  for (int i = threadIdx.x; i < 49 * 128; i += 128) w2s[i] = w2[i];
  if (threadIdx.x < 128) b1s[threadIdx.x] = b1[threadIdx.x];
  __syncthreads();
  const int p = blockIdx.x * 128 + threadIdx.x;
  float acc[49];
#pragma unroll
  for (int o = 0; o < 49; ++o) acc[o] = 0.f;
  const f16x8* ka = (const f16x8*)(kbuf + (size_t)p * 128);
  const f16x8* kb = (const f16x8*)(kbuf + (size_t)50176 * 128 + (size_t)p * 128);
  for (int u = 0; u < 16; ++u) {
    f16x8 va = ka[u], vb = kb[u];
    float kv[8];
#pragma unroll
    for (int j = 0; j < 8; ++j) {
      float s = (float)va[j] + (float)vb[j] + b1s[u * 8 + j];
      kv[j] = s > 0.f ? s : 0.f;
    }
#pragma unroll
    for (int o = 0; o < 49; ++o) {
      const float* wrow = w2s + o * 128 + u * 8;
#pragma unroll
      for (int j = 0; j < 8; ++j) acc[o] = fmaf(kv[j], wrow[j], acc[o]);
    }
  }
  float mx = -1e30f;
#pragma unroll
  for (int o = 0; o < 49; ++o) {
    float s = acc[o] + b2[o];
    float inv = gamma[o] * rsqrtf(rvar[o] + 1e-5f);
    s = (s - rmean[o]) * inv + beta[o];
    s = s > 0.f ? s : 0.f;
    acc[o] = s;
    mx = fmaxf(mx, s);
  }
  float sum = 0.f;
#pragma unroll
  for (int o = 0; o < 49; ++o) {
    float e = __expf(acc[o] - mx);
    acc[o] = e;
    sum += e;
  }
  const float rinv = 1.f / sum;
  float* orow = outs + threadIdx.x * 49;
#pragma unroll
  for (int o = 0; o < 49; ++o) orow[o] = acc[o] * rinv;
  __syncthreads();
  float* ab = attn + (size_t)blockIdx.x * (128 * 49);
  for (int i = threadIdx.x; i < 128 * 49; i += 128) ab[i] = outs[i];
}

// ---------------- attention-weighted aggregation ----------------
__global__ __launch_bounds__(896, 1) void aggregate2(
    const f16* __restrict__ xpad, const float* __restrict__ attn,
    float* __restrict__ out) {
  __shared__ float t[256][57];  // 58368 B
  const int bh = blockIdx.x;
  const int h = bh % 56, b = bh / 56;
  const int tid = threadIdx.x;
  const int wid = tid >> 6, lane = tid & 63;
  const int q = (wid < 7) ? wid * 8 : (wid - 7) * 8 + 1;

  int ap[4];
#pragma unroll
  for (int p = 0; p < 4; ++p) ap[p] = ((b * 56 + h) * 56 + q + 2 * p) * 49;

  float acc[4][4] = {};
  const f16* rowb = xpad + ((size_t)(b * 68 + h) * 68 + q) * 256 + 4 * lane;

  for (int i = 0; i < 7; ++i) {
    const f16* rb = rowb + (size_t)(2 * i * 68) * 256;
#pragma unroll
    for (int tt = 0; tt < 10; ++tt) {
      f16x4 xv = *(const f16x4*)(rb + tt * 512);  // 2 cols per tt step
      float xf[4];
#pragma unroll
      for (int k = 0; k < 4; ++k) xf[k] = (float)xv[k];
#pragma unroll
      for (int p = 0; p < 4; ++p) {
        const int j = tt - p;
        if (j >= 0 && j < 7) {
          const float a = attn[ap[p] + i * 7 + j];
#pragma unroll
          for (int k = 0; k < 4; ++k) acc[p][k] = fmaf(a, xf[k], acc[p][k]);
        }
      }
    }
  }

#pragma unroll
  for (int p = 0; p < 4; ++p)
#pragma unroll
    for (int k = 0; k < 4; ++k) t[4 * lane + k][q + 2 * p] = acc[p][k];
  __syncthreads();
  float* ob = out + ((size_t)b * 256 * 56 + h) * 56;
  for (int f = tid; f < 256 * 56; f += 896) {
    int c = f / 56, w = f % 56;
    ob[(size_t)c * 3136 + w] = t[c][w];
  }
}

// ---------------- launch ----------------
extern "C" void kernel_launch(void* const* d_in, const int* in_sizes, int n_in,
                              void* d_out, int out_size, void* d_ws,
                              size_t ws_size, hipStream_t stream) {
  const float* x = (const float*)d_in[0];
  const float* w1 = (const float*)d_in[1];
  const float* b1 = (const float*)d_in[2];
  const float* w2 = (const float*)d_in[3];
  const float* b2 = (const float*)d_in[4];
  const float* gamma = (const float*)d_in[5];
  const float* beta = (const float*)d_in[6];
  const float* rmean = (const float*)d_in[7];
  const float* rvar = (const float*)d_in[8];
  float* out = (float*)d_out;

  char* ws = (char*)d_ws;
  f16* xpad = (f16*)ws;                     // 16*68*68*256*2 = 37,879,808 B
  f16* w1h = (f16*)(ws + 37879808);         // 49*128*256*2  =  3,211,264 B
  f16* kbuf = (f16*)(ws + 41091072);        // 2*50176*128*2 = 25,690,112 B
  float* attn = (float*)(ws + 66781184);    // 50176*49*4    =  9,834,496 B

  hipLaunchKernelGGL(zero_fill, dim3(2048), dim3(256), 0, stream, (uint4*)xpad,
                     2367488);
  hipLaunchKernelGGL(transpose_cast, dim3(896), dim3(256), 0, stream, x, xpad);
  hipLaunchKernelGGL(w1_transform, dim3(6272), dim3(256), 0, stream, w1, w1h);
  hipLaunchKernelGGL(conv1_gemm, dim3(896), dim3(256), 0, stream, xpad, w1h,
                     kbuf);
  hipLaunchKernelGGL(conv2_bn_softmax, dim3(392), dim3(128), 0, stream, kbuf,
                     b1, w2, b2, gamma, beta, rmean, rvar, attn);
  hipLaunchKernelGGL(aggregate2, dim3(896), dim3(896), 0, stream, xpad, attn,
                     out);
}

// Round 6
// 306.451 us; speedup vs baseline: 1.3286x; 1.0852x over previous
//
#include <hip/hip_runtime.h>

typedef _Float16 f16;
typedef __attribute__((__ext_vector_type__(4))) _Float16 f16x4;
typedef __attribute__((__ext_vector_type__(8))) _Float16 f16x8;
typedef __attribute__((__ext_vector_type__(4))) float f32x4;

#define GLDS16(g, l) __builtin_amdgcn_global_load_lds( \
    (const __attribute__((address_space(1))) void*)(g), \
    (__attribute__((address_space(3))) void*)(l), 16, 0, 0)

// ---------------- constants ----------------
// x: (16,256,56,56)  w1: (128,256,7,7) dil=2 pad=6 -> k:(16,128,56,56)
// w2: (49,128) -> attn (16,49,56,56); out = sum_ij tap(x) * attn
// padded spatial 68x68 (orig (h,w) at padded (h+6,w+6); tap (i,j) of output
// (h,w) reads padded array index (h+2i, w+2j)).

__global__ void zero_fill(uint4* __restrict__ p, int n) {
  for (int i = blockIdx.x * blockDim.x + threadIdx.x; i < n;
       i += gridDim.x * blockDim.x)
    p[i] = make_uint4(0u, 0u, 0u, 0u);
}

// x NCHW fp32 -> xpad NHWC fp16, padded 6 each side (68x68)
__global__ __launch_bounds__(256) void transpose_cast(
    const float* __restrict__ x, f16* __restrict__ xpad) {
  __shared__ float t[256][57];
  const int bh = blockIdx.x;           // b*56 + h
  const int h = bh % 56, b = bh / 56;
  const float* xp = x + (size_t)b * 256 * 3136 + h * 56;
  for (int f = threadIdx.x; f < 256 * 56; f += 256) {
    int c = f / 56, w = f % 56;
    t[c][w] = xp[(size_t)c * 3136 + w];
  }
  __syncthreads();
  f16* op = xpad + (((size_t)(b * 68) + h + 6) * 68 + 6) * 256;
  for (int g = threadIdx.x; g < 56 * 256; g += 256) {
    int w = g / 256, c = g % 256;
    op[(size_t)w * 256 + c] = (f16)t[c][w];
  }
}

// w1 (co,c,i,j) fp32 -> per-wave-fragment lane order:
// idx = ((((ij*2+half)*4+cc)*8 + f)*64 + lane)*8 + e
//   co = f*16 + (lane&15)   [f = (f>>1)*32+(f&1)*16 form == 16f]
//   c  = half*128 + cc*32 + (lane>>4)*8 + e
__global__ void w1_transform(const float* __restrict__ w1, f16* __restrict__ w1h) {
  int idx = blockIdx.x * 256 + threadIdx.x;
  if (idx >= 49 * 128 * 256) return;
  int e = idx & 7;
  int lane = (idx >> 3) & 63;
  int f = (idx >> 9) & 7;
  int cc = (idx >> 12) & 3;
  int half = (idx >> 14) & 1;
  int ij = idx >> 15;  // 0..48
  int co = (f >> 1) * 32 + (f & 1) * 16 + (lane & 15);
  int c = half * 128 + cc * 32 + (lane >> 4) * 8 + e;
  w1h[idx] = (f16)w1[((size_t)co * 256 + c) * 49 + ij];
}

// ---------------- conv1: 4-row-strip implicit GEMM, barrier-free taps ----
// Block = (b, 4-row strip, channel-half). M=224 (14 m-frags), N=128.
// 4 waves each own 7m x 4n frags (acc[7][4]). A: 16x68x32ch strip staged
// once per cc slice (69.6KB LDS, XOR-swizzled ch-quarters for conflict-free
// ds_read_b128), reused by all 49 taps. B: global->register fragment loads
// (1KB coalesced wave-loads, L2-hot), prefetched 1 tap ahead. Barriers only
// at strip restage (8 per block).
__global__ __launch_bounds__(256, 2) void conv1_gemm(
    const f16* __restrict__ xpad, const f16* __restrict__ w1h,
    f16* __restrict__ kbuf) {
  __shared__ f16 strip[16 * 68 * 32];  // 69632 B  [r][col][ch-quarter swz]

  const int tid = threadIdx.x;
  const int wid = tid >> 6, lane = tid & 63;
  // XCD-chunked bijective swizzle (448 % 8 == 0)
  const int pphys = blockIdx.x;
  const int bid = (pphys & 7) * 56 + (pphys >> 3);
  const int half = bid & 1;
  const int sid = bid >> 1;  // 0..223
  const int b = sid / 14;
  const int h0 = (sid % 14) * 4;

  const int l15 = lane & 15;
  const int q = lane >> 4;         // ch-quarter (16B) index
  const int qb = (l15 >> 1) & 3;   // (w>>1)&3, m-independent

  const int mbase = (wid >> 1) * 7;
  const int nbase = (wid & 1) * 4;

  int arow_off[7];
#pragma unroll
  for (int mm = 0; mm < 7; ++mm) {
    int p = (mbase + mm) * 16 + l15;
    int rw = p / 56;
    int w = p - 56 * rw;
    arow_off[mm] = (rw * 68 + w) * 64;
  }

  const char* xg = (const char*)xpad +
                   ((size_t)(b * 68 + h0)) * (68 * 512) + half * 256;
  const char* wB = (const char*)w1h;
  char* Ss = (char*)strip;

  const int half4 = half * 4;
  auto loadB = [&](int cc, int ij, int nn) -> f16x8 {
    int off = (((ij * 8 + half4 + cc) * 8 + nbase + nn) * 64 + lane) * 16;
    return *(const f16x8*)(wB + off);
  };

  f32x4 acc[7][4] = {};
  f16x8 pb0 = loadB(0, 0, 0), pb1 = loadB(0, 0, 1);
  f16x8 pb2 = loadB(0, 0, 2), pb3 = loadB(0, 0, 3);

  for (int cc = 0; cc < 4; ++cc) {
    const int chb = cc * 64;  // byte offset of 32-ch slice within the half
    __syncthreads();          // prior cc's consumers done with strip
#pragma unroll
    for (int rr = 0; rr < 17; ++rr) {
      int s = rr * 256 + tid;  // 16B-slot: s = r*272 + col*4 + q4
      int r = (int)((unsigned)s / 272u);
      int rem = s - r * 272;
      int col = rem >> 2, q4 = rem & 3;
      int qq = q4 ^ ((col >> 1) & 3);  // pre-swizzled source quarter
      GLDS16(xg + (size_t)r * (68 * 512) + col * 512 + chb + qq * 16,
             Ss + (rr * 256 + wid * 64) * 16);
    }
    __syncthreads();  // strip ready

    for (int ij = 0; ij < 49; ++ij) {
      f16x8 b0 = pb0, b1 = pb1, b2 = pb2, b3 = pb3;
      int nij = ij + 1, ncc = cc;
      if (nij == 49) { nij = 0; ++ncc; }
      if (ncc < 4) {
        pb0 = loadB(ncc, nij, 0);
        pb1 = loadB(ncc, nij, 1);
        pb2 = loadB(ncc, nij, 2);
        pb3 = loadB(ncc, nij, 3);
      }
      const int i = (int)((unsigned)ij / 7u);
      const int j = ij - 7 * i;
      // read addr: (row)*4352 + (w+2j)*64 + swizzled-quarter*16
      const int base_off = i * 8704 + j * 128 + ((q ^ ((qb + j) & 3)) << 4);
#pragma unroll
      for (int mm = 0; mm < 7; ++mm) {
        f16x8 a = *(const f16x8*)(Ss + arow_off[mm] + base_off);
        acc[mm][0] = __builtin_amdgcn_mfma_f32_16x16x32_f16(a, b0,
                                                            acc[mm][0], 0, 0, 0);
        acc[mm][1] = __builtin_amdgcn_mfma_f32_16x16x32_f16(a, b1,
                                                            acc[mm][1], 0, 0, 0);
        acc[mm][2] = __builtin_amdgcn_mfma_f32_16x16x32_f16(a, b2,
                                                            acc[mm][2], 0, 0, 0);
        acc[mm][3] = __builtin_amdgcn_mfma_f32_16x16x32_f16(a, b3,
                                                            acc[mm][3], 0, 0, 0);
      }
    }
  }

  // write fp16 partials: kh[p][co], p = (b*56 + h0 + rw)*56 + w
  f16* kh = kbuf + (size_t)half * (50176 * 128);
  const int pbase = (b * 56 + h0) * 56;
#pragma unroll
  for (int mm = 0; mm < 7; ++mm) {
#pragma unroll
    for (int nn = 0; nn < 4; ++nn) {
      const int co = (nbase + nn) * 16 + l15;
#pragma unroll
      for (int r = 0; r < 4; ++r) {
        int p = (mbase + mm) * 16 + q * 4 + r;
        int rw = p / 56;
        int w = p - 56 * rw;
        kh[(size_t)(pbase + rw * 56 + w) * 128 + co] = (f16)acc[mm][nn][r];
      }
    }
  }
}

// ---------------- sum halves + bias + relu + 1x1 + BN + softmax ---------
__global__ __launch_bounds__(128) void conv2_bn_softmax(
    const f16* __restrict__ kbuf, const float* __restrict__ b1,
    const float* __restrict__ w2, const float* __restrict__ b2,
    const float* __restrict__ gamma, const float* __restrict__ beta,
    const float* __restrict__ rmean, const float* __restrict__ rvar,
    float* __restrict__ attn) {
  __shared__ float w2s[49 * 128];
  __shared__ float b1s[128];
  __shared__ float outs[128 * 49];
  for (int i = threadIdx.x; i < 49 * 128; i += 128) w2s[i] = w2[i];
  if (threadIdx.x < 128) b1s[threadIdx.x] = b1[threadIdx.x];
  __syncthreads();
  const int p = blockIdx.x * 128 + threadIdx.x;
  float acc[49];
#pragma unroll
  for (int o = 0; o < 49; ++o) acc[o] = 0.f;
  const f16x8* ka = (const f16x8*)(kbuf + (size_t)p * 128);
  const f16x8* kb = (const f16x8*)(kbuf + (size_t)50176 * 128 + (size_t)p * 128);
  for (int u = 0; u < 16; ++u) {
    f16x8 va = ka[u], vb = kb[u];
    float kv[8];
#pragma unroll
    for (int j = 0; j < 8; ++j) {
      float s = (float)va[j] + (float)vb[j] + b1s[u * 8 + j];
      kv[j] = s > 0.f ? s : 0.f;
    }
#pragma unroll
    for (int o = 0; o < 49; ++o) {
      const float* wrow = w2s + o * 128 + u * 8;
#pragma unroll
      for (int j = 0; j < 8; ++j) acc[o] = fmaf(kv[j], wrow[j], acc[o]);
    }
  }
  float mx = -1e30f;
#pragma unroll
  for (int o = 0; o < 49; ++o) {
    float s = acc[o] + b2[o];
    float inv = gamma[o] * rsqrtf(rvar[o] + 1e-5f);
    s = (s - rmean[o]) * inv + beta[o];
    s = s > 0.f ? s : 0.f;
    acc[o] = s;
    mx = fmaxf(mx, s);
  }
  float sum = 0.f;
#pragma unroll
  for (int o = 0; o < 49; ++o) {
    float e = __expf(acc[o] - mx);
    acc[o] = e;
    sum += e;
  }
  const float rinv = 1.f / sum;
  float* orow = outs + threadIdx.x * 49;
#pragma unroll
  for (int o = 0; o < 49; ++o) orow[o] = acc[o] * rinv;
  __syncthreads();
  float* ab = attn + (size_t)blockIdx.x * (128 * 49);
  for (int i = threadIdx.x; i < 128 * 49; i += 128) ab[i] = outs[i];
}

// ---------------- attention-weighted aggregation ----------------
__global__ __launch_bounds__(896, 1) void aggregate2(
    const f16* __restrict__ xpad, const float* __restrict__ attn,
    float* __restrict__ out) {
  __shared__ float t[256][57];  // 58368 B
  const int bh = blockIdx.x;
  const int h = bh % 56, b = bh / 56;
  const int tid = threadIdx.x;
  const int wid = tid >> 6, lane = tid & 63;
  const int q = (wid < 7) ? wid * 8 : (wid - 7) * 8 + 1;

  int ap[4];
#pragma unroll
  for (int p = 0; p < 4; ++p) ap[p] = ((b * 56 + h) * 56 + q + 2 * p) * 49;

  float acc[4][4] = {};
  const f16* rowb = xpad + ((size_t)(b * 68 + h) * 68 + q) * 256 + 4 * lane;

  for (int i = 0; i < 7; ++i) {
    const f16* rb = rowb + (size_t)(2 * i * 68) * 256;
#pragma unroll
    for (int tt = 0; tt < 10; ++tt) {
      f16x4 xv = *(const f16x4*)(rb + tt * 512);  // 2 cols per tt step
      float xf[4];
#pragma unroll
      for (int k = 0; k < 4; ++k) xf[k] = (float)xv[k];
#pragma unroll
      for (int p = 0; p < 4; ++p) {
        const int j = tt - p;
        if (j >= 0 && j < 7) {
          const float a = attn[ap[p] + i * 7 + j];
#pragma unroll
          for (int k = 0; k < 4; ++k) acc[p][k] = fmaf(a, xf[k], acc[p][k]);
        }
      }
    }
  }

#pragma unroll
  for (int p = 0; p < 4; ++p)
#pragma unroll
    for (int k = 0; k < 4; ++k) t[4 * lane + k][q + 2 * p] = acc[p][k];
  __syncthreads();
  float* ob = out + ((size_t)b * 256 * 56 + h) * 56;
  for (int f = tid; f < 256 * 56; f += 896) {
    int c = f / 56, w = f % 56;
    ob[(size_t)c * 3136 + w] = t[c][w];
  }
}

// ---------------- launch ----------------
extern "C" void kernel_launch(void* const* d_in, const int* in_sizes, int n_in,
                              void* d_out, int out_size, void* d_ws,
                              size_t ws_size, hipStream_t stream) {
  const float* x = (const float*)d_in[0];
  const float* w1 = (const float*)d_in[1];
  const float* b1 = (const float*)d_in[2];
  const float* w2 = (const float*)d_in[3];
  const float* b2 = (const float*)d_in[4];
  const float* gamma = (const float*)d_in[5];
  const float* beta = (const float*)d_in[6];
  const float* rmean = (const float*)d_in[7];
  const float* rvar = (const float*)d_in[8];
  float* out = (float*)d_out;

  char* ws = (char*)d_ws;
  f16* xpad = (f16*)ws;                     // 16*68*68*256*2 = 37,879,808 B
  f16* w1h = (f16*)(ws + 37879808);         // 49*128*256*2  =  3,211,264 B
  f16* kbuf = (f16*)(ws + 41091072);        // 2*50176*128*2 = 25,690,112 B
  float* attn = (float*)(ws + 66781184);    // 50176*49*4    =  9,834,496 B

  hipLaunchKernelGGL(zero_fill, dim3(2048), dim3(256), 0, stream, (uint4*)xpad,
                     2367488);
  hipLaunchKernelGGL(transpose_cast, dim3(896), dim3(256), 0, stream, x, xpad);
  hipLaunchKernelGGL(w1_transform, dim3(6272), dim3(256), 0, stream, w1, w1h);
  hipLaunchKernelGGL(conv1_gemm, dim3(448), dim3(256), 0, stream, xpad, w1h,
                     kbuf);
  hipLaunchKernelGGL(conv2_bn_softmax, dim3(392), dim3(128), 0, stream, kbuf,
                     b1, w2, b2, gamma, beta, rmean, rvar, attn);
  hipLaunchKernelGGL(aggregate2, dim3(896), dim3(896), 0, stream, xpad, attn,
                     out);
}

// Round 7
// 296.578 us; speedup vs baseline: 1.3729x; 1.0333x over previous
//
#include <hip/hip_runtime.h>

typedef _Float16 f16;
typedef __attribute__((__ext_vector_type__(4))) _Float16 f16x4;
typedef __attribute__((__ext_vector_type__(8))) _Float16 f16x8;
typedef __attribute__((__ext_vector_type__(4))) float f32x4;

#define GLDS16(g, l) __builtin_amdgcn_global_load_lds( \
    (const __attribute__((address_space(1))) void*)(g), \
    (__attribute__((address_space(3))) void*)(l), 16, 0, 0)

// ---------------- constants ----------------
// x: (16,256,56,56)  w1: (128,256,7,7) dil=2 pad=6 -> k:(16,128,56,56)
// w2: (49,128) -> attn (16,49,56,56); out = sum_ij tap(x) * attn
// padded spatial 68x68 (orig (h,w) at padded (h+6,w+6); tap (i,j) of output
// (h,w) reads padded array index (h+2i, w+2j)).

// zero only the 12.2MB border of xpad (interior is fully overwritten by
// transpose_cast): rows 0..5,62..67 full + cols 0..5,62..67 of rows 6..61.
__global__ __launch_bounds__(256) void zero_border(uint4* __restrict__ xp) {
  const int i = blockIdx.x * 256 + threadIdx.x;  // 0..761855
  int idx4;
  if (i < 417792) {  // full rows: 16b x 12r x 2176 u4
    int u = i % 2176;
    int row12 = i / 2176;
    int b = row12 / 12, r12 = row12 % 12;
    int r = (r12 < 6) ? r12 : r12 + 56;  // 0..5, 62..67
    idx4 = (b * 68 + r) * 2176 + u;
  } else {  // side runs: 16b x 56r x 2 sides x 192 u4
    int j = i - 417792;
    int u = j % 192;
    int run = j / 192;
    int side = run & 1;
    int br = run >> 1;
    int r = br % 56 + 6, b = br / 56;
    idx4 = (b * 68 + r) * 2176 + (side ? 62 * 32 : 0) + u;
  }
  xp[idx4] = make_uint4(0u, 0u, 0u, 0u);
}

// x NCHW fp32 -> xpad NHWC fp16 (interior only). f16 LDS tile; b128-clean.
__global__ __launch_bounds__(256) void transpose_cast(
    const float* __restrict__ x, f16* __restrict__ xpad) {
  __shared__ f16 t16[56][258];
  const int bh = blockIdx.x;  // b*56 + h
  const int h = bh % 56, b = bh / 56;
  const float* xp = x + (size_t)b * 256 * 3136 + h * 56;
  for (int f = threadIdx.x; f < 256 * 56; f += 256) {
    int c = f / 56, w = f % 56;
    t16[w][c] = (f16)xp[(size_t)c * 3136 + w];  // bank stride 129 -> clean
  }
  __syncthreads();
  f16* op = xpad + (((size_t)(b * 68) + h + 6) * 68 + 6) * 256;
  for (int g = threadIdx.x; g < 56 * 32; g += 256) {
    int w = g >> 5, c0 = (g & 31) * 8;
    *(f16x8*)(op + (size_t)w * 256 + c0) = *(const f16x8*)&t16[w][c0];
  }
}

// w1 (co,c,i,j) fp32 -> per-wave-fragment lane order (thread per (co,c):
// sequential 196B reads, no fetch amplification).
// layout: elem = ((((ij*8 + half*4 + cc)*8 + f)*64 + q*16 + l15)*8 + e
//   co = f*16 + l15;  c = half*128 + cc*32 + q*8 + e
__global__ __launch_bounds__(256) void w1_transform(
    const float* __restrict__ w1, f16* __restrict__ w1h) {
  const int idx = blockIdx.x * 256 + threadIdx.x;  // 0..32767
  const int co = idx >> 8, c = idx & 255;
  const int half = c >> 7, cc = (c >> 5) & 3, q = (c >> 3) & 3, e = c & 7;
  const int f = co >> 4, l15 = co & 15;
  const size_t base =
      ((((size_t)(half * 4 + cc) * 8 + f) * 64 + q * 16 + l15) * 8 + e);
  const float* src = w1 + ((size_t)co * 256 + c) * 49;
#pragma unroll 7
  for (int ij = 0; ij < 49; ++ij)
    w1h[base + (size_t)ij * 32768] = (f16)src[ij];
}

// ---------------- conv1: 4-row-strip implicit GEMM, barrier-free taps ----
// Block = (b, 4-row strip, channel-half). M=224 (14 m-frags), N=128.
// 4 waves each own 7m x 4n frags. A: 16x68x32ch strip staged once per cc
// slice (69.6KB LDS, XOR-swizzled quarters, conflict-free), reused by all
// 49 taps. B: global->register fragment loads prefetched TWO taps ahead
// (L2 latency > 1-tap compute). setprio(1) around MFMA cluster.
__global__ __launch_bounds__(256, 2) void conv1_gemm(
    const f16* __restrict__ xpad, const f16* __restrict__ w1h,
    f16* __restrict__ kbuf) {
  __shared__ f16 strip[16 * 68 * 32];  // 69632 B

  const int tid = threadIdx.x;
  const int wid = tid >> 6, lane = tid & 63;
  // XCD-chunked bijective swizzle (448 % 8 == 0)
  const int pphys = blockIdx.x;
  const int bid = (pphys & 7) * 56 + (pphys >> 3);
  const int half = bid & 1;
  const int sid = bid >> 1;  // 0..223
  const int b = sid / 14;
  const int h0 = (sid % 14) * 4;

  const int l15 = lane & 15;
  const int q = lane >> 4;        // ch-quarter (16B) index
  const int qb = (l15 >> 1) & 3;  // (w>>1)&3, m-independent

  const int mbase = (wid >> 1) * 7;
  const int nbase = (wid & 1) * 4;

  int arow_off[7];
#pragma unroll
  for (int mm = 0; mm < 7; ++mm) {
    int p = (mbase + mm) * 16 + l15;
    int rw = p / 56;
    int w = p - 56 * rw;
    arow_off[mm] = (rw * 68 + w) * 64;
  }

  const char* xg = (const char*)xpad +
                   ((size_t)(b * 68 + h0)) * (68 * 512) + half * 256;
  const char* wB = (const char*)w1h;
  char* Ss = (char*)strip;

  const int half4 = half * 4;
  auto loadB = [&](int cc, int ij, int nn) -> f16x8 {
    int off = (((ij * 8 + half4 + cc) * 8 + nbase + nn) * 64 + lane) * 16;
    return *(const f16x8*)(wB + off);
  };

  f32x4 acc[7][4] = {};
  // 2-deep B pipeline: cur = step s, nxt = step s+1; load s+2 each iter.
  f16x8 c0 = loadB(0, 0, 0), c1 = loadB(0, 0, 1);
  f16x8 c2 = loadB(0, 0, 2), c3 = loadB(0, 0, 3);
  f16x8 n0 = loadB(0, 1, 0), n1 = loadB(0, 1, 1);
  f16x8 n2 = loadB(0, 1, 2), n3 = loadB(0, 1, 3);
  int lcc = 0, lij = 2;

  for (int cc = 0; cc < 4; ++cc) {
    const int chb = cc * 64;
    __syncthreads();  // prior cc's consumers done with strip
#pragma unroll
    for (int rr = 0; rr < 17; ++rr) {
      int s = rr * 256 + tid;  // 16B-slot: s = r*272 + col*4 + q4
      int r = (int)((unsigned)s / 272u);
      int rem = s - r * 272;
      int col = rem >> 2, q4 = rem & 3;
      int qq = q4 ^ ((col >> 1) & 3);  // pre-swizzled source quarter
      GLDS16(xg + (size_t)r * (68 * 512) + col * 512 + chb + qq * 16,
             Ss + (rr * 256 + wid * 64) * 16);
    }
    __syncthreads();  // strip ready

#pragma unroll 7
    for (int ij = 0; ij < 49; ++ij) {
      f16x8 u0 = c0, u1 = c1, u2 = c2, u3 = c3;
      c0 = n0; c1 = n1; c2 = n2; c3 = n3;
      if (lcc < 4) {
        n0 = loadB(lcc, lij, 0);
        n1 = loadB(lcc, lij, 1);
        n2 = loadB(lcc, lij, 2);
        n3 = loadB(lcc, lij, 3);
        if (++lij == 49) { lij = 0; ++lcc; }
      }
      const int i = (int)((unsigned)ij / 7u);
      const int j = ij - 7 * i;
      const int base_off = i * 8704 + j * 128 + ((q ^ ((qb + j) & 3)) << 4);
      __builtin_amdgcn_s_setprio(1);
#pragma unroll
      for (int mm = 0; mm < 7; ++mm) {
        f16x8 a = *(const f16x8*)(Ss + arow_off[mm] + base_off);
        acc[mm][0] = __builtin_amdgcn_mfma_f32_16x16x32_f16(a, u0,
                                                            acc[mm][0], 0, 0, 0);
        acc[mm][1] = __builtin_amdgcn_mfma_f32_16x16x32_f16(a, u1,
                                                            acc[mm][1], 0, 0, 0);
        acc[mm][2] = __builtin_amdgcn_mfma_f32_16x16x32_f16(a, u2,
                                                            acc[mm][2], 0, 0, 0);
        acc[mm][3] = __builtin_amdgcn_mfma_f32_16x16x32_f16(a, u3,
                                                            acc[mm][3], 0, 0, 0);
      }
      __builtin_amdgcn_s_setprio(0);
    }
  }

  // write fp16 partials: kh[p][co], p = (b*56 + h0 + rw)*56 + w
  f16* kh = kbuf + (size_t)half * (50176 * 128);
  const int pbase = (b * 56 + h0) * 56;
#pragma unroll
  for (int mm = 0; mm < 7; ++mm) {
#pragma unroll
    for (int nn = 0; nn < 4; ++nn) {
      const int co = (nbase + nn) * 16 + l15;
#pragma unroll
      for (int r = 0; r < 4; ++r) {
        int p = (mbase + mm) * 16 + q * 4 + r;
        int rw = p / 56;
        int w = p - 56 * rw;
        kh[(size_t)(pbase + rw * 56 + w) * 128 + co] = (f16)acc[mm][nn][r];
      }
    }
  }
}

// ---------------- sum halves + bias + relu + 1x1 + BN + softmax ---------
__global__ __launch_bounds__(128) void conv2_bn_softmax(
    const f16* __restrict__ kbuf, const float* __restrict__ b1,
    const float* __restrict__ w2, const float* __restrict__ b2,
    const float* __restrict__ gamma, const float* __restrict__ beta,
    const float* __restrict__ rmean, const float* __restrict__ rvar,
    float* __restrict__ attn) {
  __shared__ float w2s[49 * 128];
  __shared__ float b1s[128];
  __shared__ float outs[128 * 49];
  for (int i = threadIdx.x; i < 49 * 128; i += 128) w2s[i] = w2[i];
  if (threadIdx.x < 128) b1s[threadIdx.x] = b1[threadIdx.x];
  __syncthreads();
  const int p = blockIdx.x * 128 + threadIdx.x;
  float acc[49];
#pragma unroll
  for (int o = 0; o < 49; ++o) acc[o] = 0.f;
  const f16x8* ka = (const f16x8*)(kbuf + (size_t)p * 128);
  const f16x8* kb = (const f16x8*)(kbuf + (size_t)50176 * 128 + (size_t)p * 128);
  for (int u = 0; u < 16; ++u) {
    f16x8 va = ka[u], vb = kb[u];
    float kv[8];
#pragma unroll
    for (int j = 0; j < 8; ++j) {
      float s = (float)va[j] + (float)vb[j] + b1s[u * 8 + j];
      kv[j] = s > 0.f ? s : 0.f;
    }
#pragma unroll
    for (int o = 0; o < 49; ++o) {
      const float* wrow = w2s + o * 128 + u * 8;
#pragma unroll
      for (int j = 0; j < 8; ++j) acc[o] = fmaf(kv[j], wrow[j], acc[o]);
    }
  }
  float mx = -1e30f;
#pragma unroll
  for (int o = 0; o < 49; ++o) {
    float s = acc[o] + b2[o];
    float inv = gamma[o] * rsqrtf(rvar[o] + 1e-5f);
    s = (s - rmean[o]) * inv + beta[o];
    s = s > 0.f ? s : 0.f;
    acc[o] = s;
    mx = fmaxf(mx, s);
  }
  float sum = 0.f;
#pragma unroll
  for (int o = 0; o < 49; ++o) {
    float e = __expf(acc[o] - mx);
    acc[o] = e;
    sum += e;
  }
  const float rinv = 1.f / sum;
  float* orow = outs + threadIdx.x * 49;
#pragma unroll
  for (int o = 0; o < 49; ++o) orow[o] = acc[o] * rinv;
  __syncthreads();
  float* ab = attn + (size_t)blockIdx.x * (128 * 49);
  for (int i = threadIdx.x; i < 128 * 49; i += 128) ab[i] = outs[i];
}

// ---------------- attention-weighted aggregation ----------------
__global__ __launch_bounds__(896, 1) void aggregate2(
    const f16* __restrict__ xpad, const float* __restrict__ attn,
    float* __restrict__ out) {
  __shared__ float t[256][57];  // 58368 B
  const int bh = blockIdx.x;
  const int h = bh % 56, b = bh / 56;
  const int tid = threadIdx.x;
  const int wid = tid >> 6, lane = tid & 63;
  const int q = (wid < 7) ? wid * 8 : (wid - 7) * 8 + 1;

  int ap[4];
#pragma unroll
  for (int p = 0; p < 4; ++p) ap[p] = ((b * 56 + h) * 56 + q + 2 * p) * 49;

  float acc[4][4] = {};
  const f16* rowb = xpad + ((size_t)(b * 68 + h) * 68 + q) * 256 + 4 * lane;

  for (int i = 0; i < 7; ++i) {
    const f16* rb = rowb + (size_t)(2 * i * 68) * 256;
#pragma unroll
    for (int tt = 0; tt < 10; ++tt) {
      f16x4 xv = *(const f16x4*)(rb + tt * 512);  // 2 cols per tt step
      float xf[4];
#pragma unroll
      for (int k = 0; k < 4; ++k) xf[k] = (float)xv[k];
#pragma unroll
      for (int p = 0; p < 4; ++p) {
        const int j = tt - p;
        if (j >= 0 && j < 7) {
          const float a = attn[ap[p] + i * 7 + j];
#pragma unroll
          for (int k = 0; k < 4; ++k) acc[p][k] = fmaf(a, xf[k], acc[p][k]);
        }
      }
    }
  }

#pragma unroll
  for (int p = 0; p < 4; ++p)
#pragma unroll
    for (int k = 0; k < 4; ++k) t[4 * lane + k][q + 2 * p] = acc[p][k];
  __syncthreads();
  float* ob = out + ((size_t)b * 256 * 56 + h) * 56;
  for (int f = tid; f < 256 * 56; f += 896) {
    int c = f / 56, w = f % 56;
    ob[(size_t)c * 3136 + w] = t[c][w];
  }
}

// ---------------- launch ----------------
extern "C" void kernel_launch(void* const* d_in, const int* in_sizes, int n_in,
                              void* d_out, int out_size, void* d_ws,
                              size_t ws_size, hipStream_t stream) {
  const float* x = (const float*)d_in[0];
  const float* w1 = (const float*)d_in[1];
  const float* b1 = (const float*)d_in[2];
  const float* w2 = (const float*)d_in[3];
  const float* b2 = (const float*)d_in[4];
  const float* gamma = (const float*)d_in[5];
  const float* beta = (const float*)d_in[6];
  const float* rmean = (const float*)d_in[7];
  const float* rvar = (const float*)d_in[8];
  float* out = (float*)d_out;

  char* ws = (char*)d_ws;
  f16* xpad = (f16*)ws;                     // 16*68*68*256*2 = 37,879,808 B
  f16* w1h = (f16*)(ws + 37879808);         // 49*128*256*2  =  3,211,264 B
  f16* kbuf = (f16*)(ws + 41091072);        // 2*50176*128*2 = 25,690,112 B
  float* attn = (float*)(ws + 66781184);    // 50176*49*4    =  9,834,496 B

  hipLaunchKernelGGL(zero_border, dim3(2976), dim3(256), 0, stream,
                     (uint4*)xpad);
  hipLaunchKernelGGL(transpose_cast, dim3(896), dim3(256), 0, stream, x, xpad);
  hipLaunchKernelGGL(w1_transform, dim3(128), dim3(256), 0, stream, w1, w1h);
  hipLaunchKernelGGL(conv1_gemm, dim3(448), dim3(256), 0, stream, xpad, w1h,
                     kbuf);
  hipLaunchKernelGGL(conv2_bn_softmax, dim3(392), dim3(128), 0, stream, kbuf,
                     b1, w2, b2, gamma, beta, rmean, rvar, attn);
  hipLaunchKernelGGL(aggregate2, dim3(896), dim3(896), 0, stream, xpad, attn,
                     out);
}

// Round 8
// 257.320 us; speedup vs baseline: 1.5823x; 1.1526x over previous
//
#include <hip/hip_runtime.h>

typedef _Float16 f16;
typedef __attribute__((__ext_vector_type__(2))) _Float16 f16x2;
typedef __attribute__((__ext_vector_type__(4))) _Float16 f16x4;
typedef __attribute__((__ext_vector_type__(8))) _Float16 f16x8;
typedef __attribute__((__ext_vector_type__(4))) float f32x4;

#define GLDS16(g, l) __builtin_amdgcn_global_load_lds( \
    (const __attribute__((address_space(1))) void*)(g), \
    (__attribute__((address_space(3))) void*)(l), 16, 0, 0)

// ---------------- constants ----------------
// x: (16,256,56,56)  w1: (128,256,7,7) dil=2 pad=6 -> k:(16,128,56,56)
// w2: (49,128) -> attn (16,49,56,56); out = sum_ij tap(x) * attn
// padded spatial 68x68 (orig (h,w) at padded (h+6,w+6); tap (i,j) of output
// (h,w) reads padded array index (h+2i, w+2j)).

// ---------------- fused prep: transpose+cast | zero border | w1 layout ---
// blocks 0..895: x NCHW fp32 -> xpad NHWC f16 interior row (b,h)
// blocks 896..3871: zero xpad border (12.2MB)
// blocks 3872..3999: w1 -> per-wave-fragment lane order
__global__ __launch_bounds__(256) void prep(
    const float* __restrict__ x, const float* __restrict__ w1,
    f16* __restrict__ xpad, f16* __restrict__ w1h) {
  const int blk = blockIdx.x;
  const int tid = threadIdx.x;
  if (blk < 896) {
    __shared__ f16 t16[56][258];
    const int h = blk % 56, b = blk / 56;
    const float* xp = x + (size_t)b * 256 * 3136 + h * 56;
    for (int f = tid; f < 256 * 56; f += 256) {
      int c = f / 56, w = f % 56;
      t16[w][c] = (f16)xp[(size_t)c * 3136 + w];
    }
    __syncthreads();
    f16* op = xpad + (((size_t)(b * 68) + h + 6) * 68 + 6) * 256;
    for (int g = tid; g < 56 * 32; g += 256) {
      int w = g >> 5, c0 = (g & 31) * 8;
      *(f16x8*)(op + (size_t)w * 256 + c0) = *(const f16x8*)&t16[w][c0];
    }
  } else if (blk < 896 + 2976) {
    const int i = (blk - 896) * 256 + tid;  // 0..761855
    uint4* xp4 = (uint4*)xpad;
    int idx4;
    if (i < 417792) {  // full rows: 16b x 12r x 2176 u4
      int u = i % 2176;
      int row12 = i / 2176;
      int b = row12 / 12, r12 = row12 % 12;
      int r = (r12 < 6) ? r12 : r12 + 56;
      idx4 = (b * 68 + r) * 2176 + u;
    } else {  // side runs: 16b x 56r x 2 sides x 192 u4
      int j = i - 417792;
      int u = j % 192;
      int run = j / 192;
      int side = run & 1;
      int br = run >> 1;
      int r = br % 56 + 6, b = br / 56;
      idx4 = (b * 68 + r) * 2176 + (side ? 62 * 32 : 0) + u;
    }
    xp4[idx4] = make_uint4(0u, 0u, 0u, 0u);
  } else {
    // layout: elem = (((ij*8 + half*4 + cc)*8 + f)*64 + q*16 + l15)*8 + e
    //   co = f*16 + l15;  c = half*128 + cc*32 + q*8 + e
    const int idx = (blk - 3872) * 256 + tid;  // 0..32767
    const int co = idx >> 8, c = idx & 255;
    const int half = c >> 7, cc = (c >> 5) & 3, q = (c >> 3) & 3, e = c & 7;
    const int f = co >> 4, l15 = co & 15;
    const size_t base =
        ((((size_t)(half * 4 + cc) * 8 + f) * 64 + q * 16 + l15) * 8 + e);
    const float* src = w1 + ((size_t)co * 256 + c) * 49;
#pragma unroll 7
    for (int ij = 0; ij < 49; ++ij)
      w1h[base + (size_t)ij * 32768] = (f16)src[ij];
  }
}

// ---------------- conv1: 4-row-strip implicit GEMM, barrier-free taps ----
// Block = (b, 4-row strip, channel-half). M=224 (14 m-frags), N=128.
// 4 waves each own 7m x 4n frags. A: 16x68x32ch strip staged once per cc
// slice (69.6KB LDS, XOR-swizzled quarters, conflict-free), reused by all
// 49 taps. B: global->register fragment loads, 1-tap-ahead prefetch.
// A-reads pipelined one group ahead inside the mm loop.
__global__ __launch_bounds__(256, 2) void conv1_gemm(
    const f16* __restrict__ xpad, const f16* __restrict__ w1h,
    f16* __restrict__ kbuf) {
  __shared__ f16 strip[16 * 68 * 32];  // 69632 B

  const int tid = threadIdx.x;
  const int wid = tid >> 6, lane = tid & 63;
  // XCD-chunked bijective swizzle (448 % 8 == 0)
  const int pphys = blockIdx.x;
  const int bid = (pphys & 7) * 56 + (pphys >> 3);
  const int half = bid & 1;
  const int sid = bid >> 1;  // 0..223
  const int b = sid / 14;
  const int h0 = (sid % 14) * 4;

  const int l15 = lane & 15;
  const int q = lane >> 4;        // ch-quarter (16B) index
  const int qb = (l15 >> 1) & 3;  // (w>>1)&3, m-independent

  const int mbase = (wid >> 1) * 7;
  const int nbase = (wid & 1) * 4;

  int arow_off[7];
#pragma unroll
  for (int mm = 0; mm < 7; ++mm) {
    int p = (mbase + mm) * 16 + l15;
    int rw = p / 56;
    int w = p - 56 * rw;
    arow_off[mm] = (rw * 68 + w) * 64;
  }

  const char* xg = (const char*)xpad +
                   ((size_t)(b * 68 + h0)) * (68 * 512) + half * 256;
  const char* wB = (const char*)w1h;
  char* Ss = (char*)strip;

  const int half4 = half * 4;
  auto loadB = [&](int cc, int ij, int nn) -> f16x8 {
    int off = (((ij * 8 + half4 + cc) * 8 + nbase + nn) * 64 + lane) * 16;
    return *(const f16x8*)(wB + off);
  };

  f32x4 acc[7][4] = {};
  f16x8 pb0 = loadB(0, 0, 0), pb1 = loadB(0, 0, 1);
  f16x8 pb2 = loadB(0, 0, 2), pb3 = loadB(0, 0, 3);

  for (int cc = 0; cc < 4; ++cc) {
    const int chb = cc * 64;
    __syncthreads();  // prior cc's consumers done with strip
#pragma unroll
    for (int rr = 0; rr < 17; ++rr) {
      int s = rr * 256 + tid;  // 16B-slot: s = r*272 + col*4 + q4
      int r = (int)((unsigned)s / 272u);
      int rem = s - r * 272;
      int col = rem >> 2, q4 = rem & 3;
      int qq = q4 ^ ((col >> 1) & 3);  // pre-swizzled source quarter
      GLDS16(xg + (size_t)r * (68 * 512) + col * 512 + chb + qq * 16,
             Ss + (rr * 256 + wid * 64) * 16);
    }
    __syncthreads();  // strip ready

#pragma unroll 7
    for (int ij = 0; ij < 49; ++ij) {
      f16x8 b0 = pb0, b1 = pb1, b2 = pb2, b3 = pb3;
      int nij = ij + 1, ncc = cc;
      if (nij == 49) { nij = 0; ++ncc; }
      if (ncc < 4) {
        pb0 = loadB(ncc, nij, 0);
        pb1 = loadB(ncc, nij, 1);
        pb2 = loadB(ncc, nij, 2);
        pb3 = loadB(ncc, nij, 3);
      }
      const int i = (int)((unsigned)ij / 7u);
      const int j = ij - 7 * i;
      const int base_off = i * 8704 + j * 128 + ((q ^ ((qb + j) & 3)) << 4);
      f16x8 a0 = *(const f16x8*)(Ss + arow_off[0] + base_off);
#pragma unroll
      for (int mm = 0; mm < 7; ++mm) {
        f16x8 an = a0;
        if (mm < 6) an = *(const f16x8*)(Ss + arow_off[mm + 1] + base_off);
        acc[mm][0] = __builtin_amdgcn_mfma_f32_16x16x32_f16(a0, b0,
                                                            acc[mm][0], 0, 0, 0);
        acc[mm][1] = __builtin_amdgcn_mfma_f32_16x16x32_f16(a0, b1,
                                                            acc[mm][1], 0, 0, 0);
        acc[mm][2] = __builtin_amdgcn_mfma_f32_16x16x32_f16(a0, b2,
                                                            acc[mm][2], 0, 0, 0);
        acc[mm][3] = __builtin_amdgcn_mfma_f32_16x16x32_f16(a0, b3,
                                                            acc[mm][3], 0, 0, 0);
        a0 = an;
      }
    }
  }

  // write fp16 partials: kh[p][co], p = (b*56 + h0 + rw)*56 + w
  f16* kh = kbuf + (size_t)half * (50176 * 128);
  const int pbase = (b * 56 + h0) * 56;
#pragma unroll
  for (int mm = 0; mm < 7; ++mm) {
#pragma unroll
    for (int nn = 0; nn < 4; ++nn) {
      const int co = (nbase + nn) * 16 + l15;
#pragma unroll
      for (int r = 0; r < 4; ++r) {
        int p = (mbase + mm) * 16 + q * 4 + r;
        int rw = p / 56;
        int w = p - 56 * rw;
        kh[(size_t)(pbase + rw * 56 + w) * 128 + co] = (f16)acc[mm][nn][r];
      }
    }
  }
}

// ---------------- sum halves + bias + relu + 1x1 + BN + softmax ---------
// f16 w2 in LDS + packed fdot2: halves both VALU and LDS-read chains.
__global__ __launch_bounds__(128) void conv2_bn_softmax(
    const f16* __restrict__ kbuf, const float* __restrict__ b1,
    const float* __restrict__ w2, const float* __restrict__ b2,
    const float* __restrict__ gamma, const float* __restrict__ beta,
    const float* __restrict__ rmean, const float* __restrict__ rvar,
    float* __restrict__ attn) {
  __shared__ f16 w2s[49 * 128];
  __shared__ float b1s[128];
  __shared__ float outs[128 * 49];
  for (int i = threadIdx.x; i < 49 * 128; i += 128) w2s[i] = (f16)w2[i];
  if (threadIdx.x < 128) b1s[threadIdx.x] = b1[threadIdx.x];
  __syncthreads();
  const int p = blockIdx.x * 128 + threadIdx.x;
  float acc[49];
#pragma unroll
  for (int o = 0; o < 49; ++o) acc[o] = 0.f;
  const f16x8* ka = (const f16x8*)(kbuf + (size_t)p * 128);
  const f16x8* kb = (const f16x8*)(kbuf + (size_t)50176 * 128 + (size_t)p * 128);
  for (int u = 0; u < 16; ++u) {
    f16x8 va = ka[u], vb = kb[u];
    f16x2 kvh[4];
#pragma unroll
    for (int j = 0; j < 4; ++j) {
      float s0 = (float)va[2 * j] + (float)vb[2 * j] + b1s[u * 8 + 2 * j];
      float s1 =
          (float)va[2 * j + 1] + (float)vb[2 * j + 1] + b1s[u * 8 + 2 * j + 1];
      s0 = s0 > 0.f ? s0 : 0.f;
      s1 = s1 > 0.f ? s1 : 0.f;
      kvh[j] = f16x2{(f16)s0, (f16)s1};
    }
#pragma unroll
    for (int o = 0; o < 49; ++o) {
      f16x8 wv = *(const f16x8*)(w2s + o * 128 + u * 8);
#if __has_builtin(__builtin_amdgcn_fdot2)
      acc[o] = __builtin_amdgcn_fdot2(kvh[0], f16x2{wv[0], wv[1]}, acc[o], false);
      acc[o] = __builtin_amdgcn_fdot2(kvh[1], f16x2{wv[2], wv[3]}, acc[o], false);
      acc[o] = __builtin_amdgcn_fdot2(kvh[2], f16x2{wv[4], wv[5]}, acc[o], false);
      acc[o] = __builtin_amdgcn_fdot2(kvh[3], f16x2{wv[6], wv[7]}, acc[o], false);
#else
#pragma unroll
      for (int j = 0; j < 4; ++j)
        acc[o] += (float)kvh[j][0] * (float)wv[2 * j] +
                  (float)kvh[j][1] * (float)wv[2 * j + 1];
#endif
    }
  }
  float mx = -1e30f;
#pragma unroll
  for (int o = 0; o < 49; ++o) {
    float s = acc[o] + b2[o];
    float inv = gamma[o] * rsqrtf(rvar[o] + 1e-5f);
    s = (s - rmean[o]) * inv + beta[o];
    s = s > 0.f ? s : 0.f;
    acc[o] = s;
    mx = fmaxf(mx, s);
  }
  float sum = 0.f;
#pragma unroll
  for (int o = 0; o < 49; ++o) {
    float e = __expf(acc[o] - mx);
    acc[o] = e;
    sum += e;
  }
  const float rinv = 1.f / sum;
  float* orow = outs + threadIdx.x * 49;
#pragma unroll
  for (int o = 0; o < 49; ++o) orow[o] = acc[o] * rinv;
  __syncthreads();
  float* ab = attn + (size_t)blockIdx.x * (128 * 49);
  for (int i = threadIdx.x; i < 128 * 49; i += 128) ab[i] = outs[i];
}

// ---------------- attention-weighted aggregation ----------------
// XCD-chunked mapping: each XCD gets 112 contiguous bh (2 b-slabs, 2.4MB
// each) -> xpad re-reads stay in that XCD's L2 instead of thrashing 8 L2s.
__global__ __launch_bounds__(896, 1) void aggregate2(
    const f16* __restrict__ xpad, const float* __restrict__ attn,
    float* __restrict__ out) {
  __shared__ float t[256][57];  // 58368 B
  const int pp = blockIdx.x;
  const int bh = (pp & 7) * 112 + (pp >> 3);  // bijective: 896 = 8*112
  const int h = bh % 56, b = bh / 56;
  const int tid = threadIdx.x;
  const int wid = tid >> 6, lane = tid & 63;
  const int q = (wid < 7) ? wid * 8 : (wid - 7) * 8 + 1;

  int ap[4];
#pragma unroll
  for (int p = 0; p < 4; ++p) ap[p] = ((b * 56 + h) * 56 + q + 2 * p) * 49;

  float acc[4][4] = {};
  const f16* rowb = xpad + ((size_t)(b * 68 + h) * 68 + q) * 256 + 4 * lane;

  for (int i = 0; i < 7; ++i) {
    const f16* rb = rowb + (size_t)(2 * i * 68) * 256;
#pragma unroll
    for (int tt = 0; tt < 10; ++tt) {
      f16x4 xv = *(const f16x4*)(rb + tt * 512);  // 2 cols per tt step
      float xf[4];
#pragma unroll
      for (int k = 0; k < 4; ++k) xf[k] = (float)xv[k];
#pragma unroll
      for (int p = 0; p < 4; ++p) {
        const int j = tt - p;
        if (j >= 0 && j < 7) {
          const float a = attn[ap[p] + i * 7 + j];
#pragma unroll
          for (int k = 0; k < 4; ++k) acc[p][k] = fmaf(a, xf[k], acc[p][k]);
        }
      }
    }
  }

#pragma unroll
  for (int p = 0; p < 4; ++p)
#pragma unroll
    for (int k = 0; k < 4; ++k) t[4 * lane + k][q + 2 * p] = acc[p][k];
  __syncthreads();
  float* ob = out + ((size_t)b * 256 * 56 + h) * 56;
  for (int f = tid; f < 256 * 56; f += 896) {
    int c = f / 56, w = f % 56;
    ob[(size_t)c * 3136 + w] = t[c][w];
  }
}

// ---------------- launch ----------------
extern "C" void kernel_launch(void* const* d_in, const int* in_sizes, int n_in,
                              void* d_out, int out_size, void* d_ws,
                              size_t ws_size, hipStream_t stream) {
  const float* x = (const float*)d_in[0];
  const float* w1 = (const float*)d_in[1];
  const float* b1 = (const float*)d_in[2];
  const float* w2 = (const float*)d_in[3];
  const float* b2 = (const float*)d_in[4];
  const float* gamma = (const float*)d_in[5];
  const float* beta = (const float*)d_in[6];
  const float* rmean = (const float*)d_in[7];
  const float* rvar = (const float*)d_in[8];
  float* out = (float*)d_out;

  char* ws = (char*)d_ws;
  f16* xpad = (f16*)ws;                     // 16*68*68*256*2 = 37,879,808 B
  f16* w1h = (f16*)(ws + 37879808);         // 49*128*256*2  =  3,211,264 B
  f16* kbuf = (f16*)(ws + 41091072);        // 2*50176*128*2 = 25,690,112 B
  float* attn = (float*)(ws + 66781184);    // 50176*49*4    =  9,834,496 B

  hipLaunchKernelGGL(prep, dim3(4000), dim3(256), 0, stream, x, w1, xpad, w1h);
  hipLaunchKernelGGL(conv1_gemm, dim3(448), dim3(256), 0, stream, xpad, w1h,
                     kbuf);
  hipLaunchKernelGGL(conv2_bn_softmax, dim3(392), dim3(128), 0, stream, kbuf,
                     b1, w2, b2, gamma, beta, rmean, rvar, attn);
  hipLaunchKernelGGL(aggregate2, dim3(896), dim3(896), 0, stream, xpad, attn,
                     out);
}